// Round 9
// baseline (769.179 us; speedup 1.0000x reference)
//
#include <hip/hip_runtime.h>
#include <hip/hip_cooperative_groups.h>
#include <math.h>

namespace cg = cooperative_groups;

#define NN 50000
#define EE 800000
#define ET (EE + NN)   // 850000 edges incl. self-loops
#define C  64
#define NBLK 49        // ceil(NN/1024) scan blocks
#define NCHUNK 831     // ceil(ET/1024) edge chunks
#define ZBLK 463       // zeroing blocks appended to scan_partial (fallback)
#define NTILE 782      // ceil(NN/64) node tiles
#define ETILE 13282    // ceil(ET/64) edge tiles

typedef __attribute__((ext_vector_type(8))) _Float16 f16x8;
typedef __attribute__((ext_vector_type(4))) _Float16 f16x4;
typedef __attribute__((ext_vector_type(2))) _Float16 f16x2;
typedef __attribute__((ext_vector_type(4))) float f32x4;

__device__ __forceinline__ f16x2 pk2(float a, float b) {
  return __builtin_bit_cast(f16x2, __builtin_amdgcn_cvt_pkrtz(a, b));
}
__device__ __forceinline__ f16x4 pk4(float a, float b, float c, float d) {
  return __builtin_shufflevector(pk2(a, b), pk2(c, d), 0, 1, 2, 3);
}
__device__ __forceinline__ f16x8 pk8(const float* y) {
  const f16x4 lo = pk4(y[0], y[1], y[2], y[3]);
  const f16x4 hi = pk4(y[4], y[5], y[6], y[7]);
  return __builtin_shufflevector(lo, hi, 0, 1, 2, 3, 4, 5, 6, 7);
}

__device__ __forceinline__ f16x8 frag_ldh(const _Float16* base, int row,
                                          int kofs) {
  return *(const f16x8*)(base + row * 72 + kofs);
}

// Copy one 64x64 f16 weight from global (row-major 64) to LDS (stride 72).
__device__ __forceinline__ void stage_w(_Float16* __restrict__ dst,
                                        const _Float16* __restrict__ src16,
                                        int tid) {
  const f16x8* src = (const f16x8*)(src16 + tid * 16);
  _Float16* d = dst + (tid >> 2) * 72 + (tid & 3) * 16;
  ((f16x8*)d)[0] = src[0];
  ((f16x8*)d)[1] = src[1];
}

// ===========================================================================
// MEGA (cooperative) kernel
// ===========================================================================
struct MegaArgs {
  const float *x, *pos;
  const int* ei;
  const float *W_in, *b_in, *W_out, *b_out, *W_lin, *W_src, *W_dst;
  const float *pos_w1, *pos_b1, *pos_w2, *pos_b2;
  const float *att_w1, *att_b1, *att_w2, *att_b2;
  float *num, *den;
  _Float16 *vh, *kh, *qh, *w16;
  int *cnt2, *curs2, *bsum;
  int2* srt;
  float* out;
};

__global__ __launch_bounds__(256, 4) void mega_kernel(MegaArgs a) {
  cg::grid_group grd = cg::this_grid();
  __shared__ __align__(16) _Float16 smem[18432];
  __shared__ __align__(16) float posw1T[192];
  __shared__ float b1s[64], b2s[64], pb1s[64], pb2s[64];
  __shared__ int dsts[64];

  const int tid = threadIdx.x;
  const int bid = blockIdx.x;
  const int gsz = gridDim.x;
  const int l15 = tid & 15;
  const int quad = (tid >> 4) & 3;
  const int wband = tid >> 6;

  // ---------------- P0: zero num/den + cnt2, convert weights -------------
  {
    const int gt = bid * 256 + tid;
    const int stride = gsz * 256;
    float4* z1 = (float4*)a.num;  // num & den contiguous
    const float4 zf = make_float4(0.f, 0.f, 0.f, 0.f);
#pragma unroll 1
    for (int i = gt; i < (2 * NN * C) / 4; i += stride) z1[i] = zf;
    int4* z2 = (int4*)a.cnt2;
    const int4 zi = make_int4(0, 0, 0, 0);
#pragma unroll 1
    for (int i = gt; i < (8 * NN) / 4; i += stride) z2[i] = zi;
    if (bid < 8) {
      const float* Ws[8] = {a.W_in,   a.W_lin,  a.W_src,  a.W_dst,
                            a.att_w1, a.att_w2, a.pos_w2, a.W_out};
      const float* src = Ws[bid];
      _Float16* dst = a.w16 + bid * 4096;
#pragma unroll 1
      for (int i = tid * 4; i < 4096; i += 1024) {
        const float4 w = *(const float4*)(src + i);
        *(f16x4*)(dst + i) = pk4(w.x, w.y, w.z, w.w);
      }
    }
  }
  grd.sync();

  // ---------------- P1: sharded histogram + node projections -------------
  {
#pragma unroll 1
    for (int chunk = bid; chunk < NCHUNK; chunk += gsz) {
      int* cs = a.cnt2 + (chunk & 7) * NN;
      const int e0 = chunk * 1024 + tid * 4;
      if (e0 < ET) {
        int d[4];
        if (e0 + 3 < EE) {
          const int4 dv = *(const int4*)(a.ei + EE + e0);
          d[0] = dv.x; d[1] = dv.y; d[2] = dv.z; d[3] = dv.w;
        } else {
#pragma unroll
          for (int i = 0; i < 4; ++i) {
            const int e = e0 + i;
            d[i] = (e < EE) ? a.ei[EE + e] : ((e < ET) ? e - EE : -1);
          }
        }
#pragma unroll
        for (int i = 0; i < 4; ++i)
          if (d[i] >= 0) atomicAdd(&cs[d[i]], 1);
      }
    }
    // node tiles: smem = [A:W_in->W_dst | B:W_lin | C:W_src | D:hlds]
    _Float16* A = smem;
    _Float16* B = smem + 4608;
    _Float16* Cr = smem + 9216;
    _Float16* D = smem + 13824;
#pragma unroll 1
    for (int tile = bid; tile < NTILE; tile += gsz) {
      __syncthreads();  // protect smem from previous tile
      const int nloc = wband * 16 + l15;
      const int gn = tile * 64 + nloc;
      stage_w(A, a.w16 + 0 * 4096, tid);
      stage_w(B, a.w16 + 1 * 4096, tid);
      stage_w(Cr, a.w16 + 2 * 4096, tid);
      if (tid < 64) b1s[tid] = a.b_in[tid];
      f16x8 bfrag[2];
#pragma unroll
      for (int ks = 0; ks < 2; ++ks) {
        float y[8] = {0.f, 0.f, 0.f, 0.f, 0.f, 0.f, 0.f, 0.f};
        if (gn < NN) {
          const size_t base = (size_t)gn * 64 + ks * 32 + quad * 8;
          const float4 p = *(const float4*)(a.x + base);
          const float4 q = *(const float4*)(a.x + base + 4);
          y[0] = p.x; y[1] = p.y; y[2] = p.z; y[3] = p.w;
          y[4] = q.x; y[5] = q.y; y[6] = q.z; y[7] = q.w;
        }
        bfrag[ks] = pk8(y);
      }
      __syncthreads();  // B0
      // GEMM1: h = relu(W_in . x^T + b) -> D rows [n][o]
#pragma unroll
      for (int t = 0; t < 4; ++t) {
        f32x4 acc = {0.f, 0.f, 0.f, 0.f};
#pragma unroll
        for (int ks = 0; ks < 2; ++ks) {
          const f16x8 af = frag_ldh(A, t * 16 + l15, ks * 32 + quad * 8);
          acc = __builtin_amdgcn_mfma_f32_16x16x32_f16(af, bfrag[ks], acc, 0, 0, 0);
        }
        const int hb = t * 16 + quad * 4;
        *(f16x4*)(D + nloc * 72 + hb) = pk4(
            fmaxf(acc[0] + b1s[hb + 0], 0.f), fmaxf(acc[1] + b1s[hb + 1], 0.f),
            fmaxf(acc[2] + b1s[hb + 2], 0.f), fmaxf(acc[3] + b1s[hb + 3], 0.f));
      }
      __syncthreads();  // B1
      f16x8 hfrag[2];
#pragma unroll
      for (int ks = 0; ks < 2; ++ks)
        hfrag[ks] = frag_ldh(D, nloc, ks * 32 + quad * 8);
      stage_w(A, a.w16 + 3 * 4096, tid);  // W_dst over W_in (safe post-B1)
      _Float16* outs2[2] = {a.vh, a.kh};
      const _Float16* Ws2[2] = {B, Cr};
#pragma unroll
      for (int p = 0; p < 2; ++p) {
#pragma unroll
        for (int t = 0; t < 4; ++t) {
          f32x4 acc = {0.f, 0.f, 0.f, 0.f};
#pragma unroll
          for (int ks = 0; ks < 2; ++ks) {
            const f16x8 af = frag_ldh(Ws2[p], t * 16 + l15, ks * 32 + quad * 8);
            acc = __builtin_amdgcn_mfma_f32_16x16x32_f16(af, hfrag[ks], acc, 0, 0, 0);
          }
          if (gn < NN)
            *(f16x4*)(outs2[p] + (size_t)gn * 64 + t * 16 + quad * 4) =
                pk4(acc[0], acc[1], acc[2], acc[3]);
        }
      }
      __syncthreads();  // B2: W_dst staged
#pragma unroll
      for (int t = 0; t < 4; ++t) {
        f32x4 acc = {0.f, 0.f, 0.f, 0.f};
#pragma unroll
        for (int ks = 0; ks < 2; ++ks) {
          const f16x8 af = frag_ldh(A, t * 16 + l15, ks * 32 + quad * 8);
          acc = __builtin_amdgcn_mfma_f32_16x16x32_f16(af, hfrag[ks], acc, 0, 0, 0);
        }
        if (gn < NN)
          *(f16x4*)(a.qh + (size_t)gn * 64 + t * 16 + quad * 4) =
              pk4(acc[0], acc[1], acc[2], acc[3]);
      }
    }
  }
  grd.sync();

  // ---------------- P2a: scan partial sums --------------------------------
  {
    int* wsb = (int*)smem;
#pragma unroll 1
    for (int sb = bid; sb < NBLK; sb += gsz) {
      __syncthreads();
      const int base = sb * 1024 + tid * 4;
      int s = 0;
      if (base + 3 < NN) {
#pragma unroll
        for (int sh = 0; sh < 8; ++sh) {
          const int4 v = *(const int4*)(a.cnt2 + sh * NN + base);
          s += v.x + v.y + v.z + v.w;
        }
      } else {
#pragma unroll
        for (int i = 0; i < 4; ++i)
          if (base + i < NN)
#pragma unroll
            for (int sh = 0; sh < 8; ++sh) s += a.cnt2[sh * NN + base + i];
      }
#pragma unroll
      for (int off = 32; off; off >>= 1) s += __shfl_down(s, off, 64);
      if ((tid & 63) == 0) wsb[tid >> 6] = s;
      __syncthreads();
      if (tid == 0) a.bsum[sb] = wsb[0] + wsb[1] + wsb[2] + wsb[3];
    }
  }
  grd.sync();

  // ---------------- P2b: scan final (per-shard cursor bases) --------------
  {
    int* tsum = (int*)smem;          // 256 ints
    int* sblk = ((int*)smem) + 256;  // 64 ints
#pragma unroll 1
    for (int sb = bid; sb < NBLK; sb += gsz) {
      __syncthreads();
      if (tid < 64) {
        const int mine = (tid < NBLK) ? a.bsum[tid] : 0;
        int v = mine;
#pragma unroll
        for (int off = 1; off < 64; off <<= 1) {
          const int u = __shfl_up(v, off, 64);
          if (tid >= off) v += u;
        }
        sblk[tid] = v - mine;
      }
      const int base = sb * 1024 + tid * 4;
      int c2[8][4];
      int v[4] = {0, 0, 0, 0};
      if (base + 3 < NN) {
#pragma unroll
        for (int sh = 0; sh < 8; ++sh) {
          const int4 xx = *(const int4*)(a.cnt2 + sh * NN + base);
          c2[sh][0] = xx.x; c2[sh][1] = xx.y; c2[sh][2] = xx.z; c2[sh][3] = xx.w;
          v[0] += xx.x; v[1] += xx.y; v[2] += xx.z; v[3] += xx.w;
        }
      } else {
#pragma unroll
        for (int sh = 0; sh < 8; ++sh)
#pragma unroll
          for (int i = 0; i < 4; ++i) {
            const int c = (base + i < NN) ? a.cnt2[sh * NN + base + i] : 0;
            c2[sh][i] = c;
            v[i] += c;
          }
      }
      const int s = v[0] + v[1] + v[2] + v[3];
      tsum[tid] = s;
      __syncthreads();
      for (int off = 1; off < 256; off <<= 1) {
        const int u = (tid >= off) ? tsum[tid - off] : 0;
        __syncthreads();
        tsum[tid] += u;
        __syncthreads();
      }
      int ex = sblk[sb] + tsum[tid] - s;
      int offs[8][4];
#pragma unroll
      for (int i = 0; i < 4; ++i) {
        int run = ex;
#pragma unroll
        for (int sh = 0; sh < 8; ++sh) {
          offs[sh][i] = run;
          run += c2[sh][i];
        }
        ex += v[i];
      }
      if (base + 3 < NN) {
#pragma unroll
        for (int sh = 0; sh < 8; ++sh)
          *(int4*)(a.curs2 + sh * NN + base) =
              make_int4(offs[sh][0], offs[sh][1], offs[sh][2], offs[sh][3]);
      } else {
#pragma unroll
        for (int sh = 0; sh < 8; ++sh)
#pragma unroll
          for (int i = 0; i < 4; ++i)
            if (base + i < NN) a.curs2[sh * NN + base + i] = offs[sh][i];
      }
    }
  }
  grd.sync();

  // ---------------- P3: scatter -------------------------------------------
  {
#pragma unroll 1
    for (int chunk = bid; chunk < NCHUNK; chunk += gsz) {
      int* cs = a.curs2 + (chunk & 7) * NN;
      const int e0 = chunk * 1024 + tid * 4;
      if (e0 < ET) {
        int s[4], d[4];
        if (e0 + 3 < EE) {
          const int4 sv = *(const int4*)(a.ei + e0);
          const int4 dv = *(const int4*)(a.ei + EE + e0);
          s[0] = sv.x; s[1] = sv.y; s[2] = sv.z; s[3] = sv.w;
          d[0] = dv.x; d[1] = dv.y; d[2] = dv.z; d[3] = dv.w;
        } else {
#pragma unroll
          for (int i = 0; i < 4; ++i) {
            const int e = e0 + i;
            if (e < EE) {
              s[i] = a.ei[e];
              d[i] = a.ei[EE + e];
            } else if (e < ET) {
              s[i] = d[i] = e - EE;
            } else {
              s[i] = d[i] = -1;
            }
          }
        }
#pragma unroll
        for (int i = 0; i < 4; ++i) {
          if (d[i] >= 0) {
            const int p = atomicAdd(&cs[d[i]], 1);
            a.srt[p] = make_int2(s[i], d[i]);
          }
        }
      }
    }
  }
  grd.sync();

  // ---------------- P4: edge pass (grid-stride tiles) ---------------------
  {
    _Float16* W1 = smem;
    _Float16* W2 = smem + 4608;
    _Float16* PW2 = smem + 9216;
    _Float16* h1 = smem + 13824;
    float2* pairb = (float2*)smem;
    if (tid < 64) {
      b1s[tid] = a.att_b1[tid];
      b2s[tid] = a.att_b2[tid];
      pb1s[tid] = a.pos_b1[tid];
      pb2s[tid] = a.pos_b2[tid];
      posw1T[0 * 64 + tid] = a.pos_w1[tid * 3 + 0];
      posw1T[1 * 64 + tid] = a.pos_w1[tid * 3 + 1];
      posw1T[2 * 64 + tid] = a.pos_w1[tid * 3 + 2];
    }
    const int eloc = wband * 16 + l15;
#pragma unroll 1
    for (int tile = bid; tile < ETILE; tile += gsz) {
      __syncthreads();  // protect smem/dsts from previous tile phase6
      const int eb = tile * 64;
      int s_mine, d_mine;
      f16x8 bfrag[2];
      float dp0, dp1, dp2;
      {
        const int e = eb + eloc;
        int2 sd = make_int2(0, 0);
        int valid_d = -1;
        if (e < ET) {
          sd = a.srt[e];
          valid_d = sd.y;
        }
        s_mine = sd.x;
        d_mine = sd.y;
        if (quad == 0) dsts[eloc] = valid_d;
#pragma unroll
        for (int ks = 0; ks < 2; ++ks) {
          const f16x8 qv =
              *(const f16x8*)(a.qh + (size_t)d_mine * 64 + ks * 32 + quad * 8);
          const f16x8 kv =
              *(const f16x8*)(a.kh + (size_t)s_mine * 64 + ks * 32 + quad * 8);
          bfrag[ks] = qv - kv;
        }
        dp0 = a.pos[(size_t)d_mine * 3 + 0] - a.pos[(size_t)s_mine * 3 + 0];
        dp1 = a.pos[(size_t)d_mine * 3 + 1] - a.pos[(size_t)s_mine * 3 + 1];
        dp2 = a.pos[(size_t)d_mine * 3 + 2] - a.pos[(size_t)s_mine * 3 + 2];
      }
      stage_w(W1, a.w16 + 4 * 4096, tid);
      stage_w(W2, a.w16 + 5 * 4096, tid);
      stage_w(PW2, a.w16 + 6 * 4096, tid);
      __syncthreads();  // B0

#pragma unroll
      for (int t = 0; t < 4; ++t) {
        f32x4 acc = {0.f, 0.f, 0.f, 0.f};
#pragma unroll
        for (int ks = 0; ks < 2; ++ks) {
          const f16x8 af = frag_ldh(W1, t * 16 + l15, ks * 32 + quad * 8);
          acc = __builtin_amdgcn_mfma_f32_16x16x32_f16(af, bfrag[ks], acc, 0, 0, 0);
        }
        const int hb = t * 16 + quad * 4;
        *(f16x4*)(h1 + eloc * 72 + hb) = pk4(
            fmaxf(acc[0] + b1s[hb + 0], 0.f), fmaxf(acc[1] + b1s[hb + 1], 0.f),
            fmaxf(acc[2] + b1s[hb + 2], 0.f), fmaxf(acc[3] + b1s[hb + 3], 0.f));
      }
      f16x8 hpfrag[2];
#pragma unroll
      for (int ks = 0; ks < 2; ++ks) {
        float hv[8];
#pragma unroll
        for (int j = 0; j < 8; ++j) {
          const int i = ks * 32 + quad * 8 + j;
          float h = pb1s[i];
          h = fmaf(dp0, posw1T[i], h);
          h = fmaf(dp1, posw1T[64 + i], h);
          h = fmaf(dp2, posw1T[128 + i], h);
          hv[j] = fmaxf(h, 0.f);
        }
        hpfrag[ks] = pk8(hv);
      }
      __syncthreads();  // B1
      float ex[16], del[16];
      {
        f16x8 hfrag[2];
#pragma unroll
        for (int ks = 0; ks < 2; ++ks)
          hfrag[ks] = frag_ldh(h1, eloc, ks * 32 + quad * 8);
#pragma unroll
        for (int t = 0; t < 4; ++t) {
          f32x4 acc = {0.f, 0.f, 0.f, 0.f};
#pragma unroll
          for (int ks = 0; ks < 2; ++ks) {
            const f16x8 af = frag_ldh(W2, t * 16 + l15, ks * 32 + quad * 8);
            acc = __builtin_amdgcn_mfma_f32_16x16x32_f16(af, hfrag[ks], acc, 0, 0, 0);
          }
          const int ob = t * 16 + quad * 4;
#pragma unroll
          for (int r = 0; r < 4; ++r)
            ex[t * 4 + r] = __expf(fmaxf(acc[r] + b2s[ob + r], 0.f));
        }
      }
#pragma unroll
      for (int t = 0; t < 4; ++t) {
        f32x4 acc = {0.f, 0.f, 0.f, 0.f};
#pragma unroll
        for (int ks = 0; ks < 2; ++ks) {
          const f16x8 af = frag_ldh(PW2, t * 16 + l15, ks * 32 + quad * 8);
          acc = __builtin_amdgcn_mfma_f32_16x16x32_f16(af, hpfrag[ks], acc, 0, 0, 0);
        }
        const int ob = t * 16 + quad * 4;
#pragma unroll
        for (int r = 0; r < 4; ++r)
          del[t * 4 + r] = fmaxf(acc[r] + pb2s[ob + r], 0.f);
      }
      float vr[16];
#pragma unroll
      for (int t = 0; t < 4; ++t) {
        const f16x4 v4 =
            *(const f16x4*)(a.vh + (size_t)s_mine * 64 + t * 16 + quad * 4);
        vr[t * 4 + 0] = (float)v4[0];
        vr[t * 4 + 1] = (float)v4[1];
        vr[t * 4 + 2] = (float)v4[2];
        vr[t * 4 + 3] = (float)v4[3];
      }
      __syncthreads();  // B2
#pragma unroll
      for (int t = 0; t < 4; ++t) {
#pragma unroll
        for (int r = 0; r < 4; ++r) {
          const int o = t * 16 + quad * 4 + r;
          const int sl = (eloc + 2 * o) & 63;
          const float e_ = ex[t * 4 + r];
          pairb[o * 65 + sl] =
              make_float2(e_ * (vr[t * 4 + r] + del[t * 4 + r]), e_);
        }
      }
      __syncthreads();  // B3
      {
        const int c = tid & 63;
        const int r = tid >> 6;
        float am = 0.f, ae = 0.f;
        int cur = -1;
#pragma unroll 1
        for (int t2 = 0; t2 < 16; ++t2) {
          const int el = r * 16 + t2;
          const int d = dsts[el];
          if (d != cur) {
            if (cur >= 0) {
              unsafeAtomicAdd(a.num + (size_t)cur * 64 + c, am);
              unsafeAtomicAdd(a.den + (size_t)cur * 64 + c, ae);
            }
            cur = d;
            am = 0.f;
            ae = 0.f;
          }
          if (d >= 0) {
            const float2 pe = pairb[c * 65 + ((el + 2 * c) & 63)];
            am += pe.x;
            ae += pe.y;
          }
        }
        if (cur >= 0) {
          unsafeAtomicAdd(a.num + (size_t)cur * 64 + c, am);
          unsafeAtomicAdd(a.den + (size_t)cur * 64 + c, ae);
        }
      }
    }
  }
  grd.sync();

  // ---------------- P5: out projection ------------------------------------
  {
    __syncthreads();
    stage_w(smem, a.w16 + 7 * 4096, tid);
    if (tid < 64) b1s[tid] = a.b_out[tid];
    __syncthreads();
#pragma unroll 1
    for (int tile = bid; tile < NTILE; tile += gsz) {
      const int gn = tile * 64 + wband * 16 + l15;
      f16x8 bfrag[2];
#pragma unroll
      for (int ks = 0; ks < 2; ++ks) {
        float y[8] = {0.f, 0.f, 0.f, 0.f, 0.f, 0.f, 0.f, 0.f};
        if (gn < NN) {
          const size_t base = (size_t)gn * 64 + ks * 32 + quad * 8;
          const float4 n0 = *(const float4*)(a.num + base);
          const float4 n1 = *(const float4*)(a.num + base + 4);
          const float4 d0 = *(const float4*)(a.den + base);
          const float4 d1 = *(const float4*)(a.den + base + 4);
          y[0] = n0.x / (d0.x + 1e-16f); y[1] = n0.y / (d0.y + 1e-16f);
          y[2] = n0.z / (d0.z + 1e-16f); y[3] = n0.w / (d0.w + 1e-16f);
          y[4] = n1.x / (d1.x + 1e-16f); y[5] = n1.y / (d1.y + 1e-16f);
          y[6] = n1.z / (d1.z + 1e-16f); y[7] = n1.w / (d1.w + 1e-16f);
        }
        bfrag[ks] = pk8(y);
      }
#pragma unroll
      for (int t = 0; t < 4; ++t) {
        f32x4 acc = {0.f, 0.f, 0.f, 0.f};
#pragma unroll
        for (int ks = 0; ks < 2; ++ks) {
          const f16x8 af = frag_ldh(smem, t * 16 + l15, ks * 32 + quad * 8);
          acc = __builtin_amdgcn_mfma_f32_16x16x32_f16(af, bfrag[ks], acc, 0, 0, 0);
        }
        if (gn < NN) {
          const int ob = t * 16 + quad * 4;
          float4 r;
          r.x = fmaxf(acc[0] + b1s[ob + 0], 0.f);
          r.y = fmaxf(acc[1] + b1s[ob + 1], 0.f);
          r.z = fmaxf(acc[2] + b1s[ob + 2], 0.f);
          r.w = fmaxf(acc[3] + b1s[ob + 3], 0.f);
          *(float4*)(a.out + (size_t)gn * 64 + ob) = r;
        }
      }
    }
  }
}

// ===========================================================================
// FALLBACK pipeline (R8, verbatim) — used only if cooperative launch fails
// ===========================================================================
__global__ __launch_bounds__(256) void prep_kernel(
    const float* __restrict__ W_in, const float* __restrict__ W_lin,
    const float* __restrict__ W_src, const float* __restrict__ W_dst,
    const float* __restrict__ att_w1, const float* __restrict__ att_w2,
    const float* __restrict__ pos_w2, const float* __restrict__ W_out,
    _Float16* __restrict__ w16, int* __restrict__ cnt2) {
  const float* Ws[8] = {W_in, W_lin, W_src, W_dst, att_w1, att_w2, pos_w2, W_out};
  const float* src = Ws[blockIdx.x];
  _Float16* dst = w16 + blockIdx.x * 4096;
#pragma unroll
  for (int i = threadIdx.x * 4; i < 4096; i += 1024) {
    const float4 w = *(const float4*)(src + i);
    *(f16x4*)(dst + i) = pk4(w.x, w.y, w.z, w.w);
  }
  int4* cz = (int4*)(cnt2 + blockIdx.x * NN);
#pragma unroll 1
  for (int i = threadIdx.x; i < NN / 4; i += 256) cz[i] = make_int4(0, 0, 0, 0);
}

__global__ __launch_bounds__(256) void scan_partial(const int* __restrict__ cnt2,
                                                    int* __restrict__ bsum,
                                                    float* __restrict__ zeroreg) {
  const int t = threadIdx.x;
  if (blockIdx.x >= NBLK) {
    const int zb = blockIdx.x - NBLK;
    float4* dst = (float4*)zeroreg;
    const int total4 = 2 * NN * 64 / 4;
    const float4 z = make_float4(0.f, 0.f, 0.f, 0.f);
#pragma unroll 1
    for (int i = zb * 256 + t; i < total4; i += ZBLK * 256) dst[i] = z;
    return;
  }
  __shared__ int ws[4];
  const int base = blockIdx.x * 1024 + t * 4;
  int s = 0;
  if (base + 3 < NN) {
#pragma unroll
    for (int sh = 0; sh < 8; ++sh) {
      const int4 v = *(const int4*)(cnt2 + sh * NN + base);
      s += v.x + v.y + v.z + v.w;
    }
  } else {
#pragma unroll
    for (int i = 0; i < 4; ++i)
      if (base + i < NN)
#pragma unroll
        for (int sh = 0; sh < 8; ++sh) s += cnt2[sh * NN + base + i];
  }
#pragma unroll
  for (int off = 32; off; off >>= 1) s += __shfl_down(s, off, 64);
  if ((t & 63) == 0) ws[t >> 6] = s;
  __syncthreads();
  if (t == 0) bsum[blockIdx.x] = ws[0] + ws[1] + ws[2] + ws[3];
}

__global__ __launch_bounds__(256) void scan_final(const int* __restrict__ cnt2,
                                                  const int* __restrict__ bsum,
                                                  int* __restrict__ curs2) {
  __shared__ int tsum[256];
  __shared__ int sblk[64];
  const int t = threadIdx.x;
  if (t < 64) {
    const int mine = (t < NBLK) ? bsum[t] : 0;
    int v = mine;
#pragma unroll
    for (int off = 1; off < 64; off <<= 1) {
      const int u = __shfl_up(v, off, 64);
      if (t >= off) v += u;
    }
    sblk[t] = v - mine;
  }
  const int base = blockIdx.x * 1024 + t * 4;
  int c2[8][4];
  int v[4] = {0, 0, 0, 0};
  if (base + 3 < NN) {
#pragma unroll
    for (int sh = 0; sh < 8; ++sh) {
      const int4 x = *(const int4*)(cnt2 + sh * NN + base);
      c2[sh][0] = x.x; c2[sh][1] = x.y; c2[sh][2] = x.z; c2[sh][3] = x.w;
      v[0] += x.x; v[1] += x.y; v[2] += x.z; v[3] += x.w;
    }
  } else {
#pragma unroll
    for (int sh = 0; sh < 8; ++sh)
#pragma unroll
      for (int i = 0; i < 4; ++i) {
        const int c = (base + i < NN) ? cnt2[sh * NN + base + i] : 0;
        c2[sh][i] = c;
        v[i] += c;
      }
  }
  const int s = v[0] + v[1] + v[2] + v[3];
  tsum[t] = s;
  __syncthreads();
  for (int off = 1; off < 256; off <<= 1) {
    const int u = (t >= off) ? tsum[t - off] : 0;
    __syncthreads();
    tsum[t] += u;
    __syncthreads();
  }
  int ex = sblk[blockIdx.x] + tsum[t] - s;
  int offs[8][4];
#pragma unroll
  for (int i = 0; i < 4; ++i) {
    int run = ex;
#pragma unroll
    for (int sh = 0; sh < 8; ++sh) {
      offs[sh][i] = run;
      run += c2[sh][i];
    }
    ex += v[i];
  }
  if (base + 3 < NN) {
#pragma unroll
    for (int sh = 0; sh < 8; ++sh)
      *(int4*)(curs2 + sh * NN + base) =
          make_int4(offs[sh][0], offs[sh][1], offs[sh][2], offs[sh][3]);
  } else {
#pragma unroll
    for (int sh = 0; sh < 8; ++sh)
#pragma unroll
      for (int i = 0; i < 4; ++i)
        if (base + i < NN) curs2[sh * NN + base + i] = offs[sh][i];
  }
}

__global__ void scatter_kernel(const int* __restrict__ ei,
                               int* __restrict__ curs2, int2* __restrict__ srt) {
  const int chunk = blockIdx.x;
  int* cs = curs2 + (chunk & 7) * NN;
  const int e0 = chunk * 1024 + threadIdx.x * 4;
  if (e0 >= ET) return;
  int s[4], d[4];
  if (e0 + 3 < EE) {
    const int4 sv = *(const int4*)(ei + e0);
    const int4 dv = *(const int4*)(ei + EE + e0);
    s[0] = sv.x; s[1] = sv.y; s[2] = sv.z; s[3] = sv.w;
    d[0] = dv.x; d[1] = dv.y; d[2] = dv.z; d[3] = dv.w;
  } else {
#pragma unroll
    for (int i = 0; i < 4; ++i) {
      const int e = e0 + i;
      if (e < EE) {
        s[i] = ei[e];
        d[i] = ei[EE + e];
      } else if (e < ET) {
        s[i] = d[i] = e - EE;
      } else {
        s[i] = d[i] = -1;
      }
    }
  }
#pragma unroll
  for (int i = 0; i < 4; ++i) {
    if (d[i] >= 0) {
      const int p = atomicAdd(&cs[d[i]], 1);
      srt[p] = make_int2(s[i], d[i]);
    }
  }
}

__global__ __launch_bounds__(256, 3) void node_proj(
    const float* __restrict__ x, const float* __restrict__ b_in,
    const _Float16* __restrict__ w16, const int* __restrict__ ei,
    int* __restrict__ cnt2, _Float16* __restrict__ vh,
    _Float16* __restrict__ kh, _Float16* __restrict__ qh) {
  __shared__ __align__(16) _Float16 wlds[4 * 4608];
  __shared__ __align__(16) _Float16 hlds[4608];
  __shared__ float biasv[64];

  const int tid = threadIdx.x;
  const int nb = blockIdx.x * 64;
  const int l15 = tid & 15;
  const int quad = (tid >> 4) & 3;
  const int wband = tid >> 6;
  const int nloc = wband * 16 + l15;
  const int gn = nb + nloc;

#pragma unroll 1
  for (int chunk = blockIdx.x; chunk < NCHUNK; chunk += gridDim.x) {
    int* cs = cnt2 + (chunk & 7) * NN;
    const int e0 = chunk * 1024 + tid * 4;
    if (e0 < ET) {
      int d[4];
      if (e0 + 3 < EE) {
        const int4 dv = *(const int4*)(ei + EE + e0);
        d[0] = dv.x; d[1] = dv.y; d[2] = dv.z; d[3] = dv.w;
      } else {
#pragma unroll
        for (int i = 0; i < 4; ++i) {
          const int e = e0 + i;
          d[i] = (e < EE) ? ei[EE + e] : ((e < ET) ? e - EE : -1);
        }
      }
#pragma unroll
      for (int i = 0; i < 4; ++i)
        if (d[i] >= 0) atomicAdd(&cs[d[i]], 1);
    }
  }

#pragma unroll
  for (int w = 0; w < 4; ++w) stage_w(wlds + w * 4608, w16 + w * 4096, tid);
  if (tid < 64) biasv[tid] = b_in[tid];

  f16x8 bfrag[2];
#pragma unroll
  for (int ks = 0; ks < 2; ++ks) {
    float y[8] = {0.f, 0.f, 0.f, 0.f, 0.f, 0.f, 0.f, 0.f};
    if (gn < NN) {
      const float4 p = *(const float4*)(x + (size_t)gn * 64 + ks * 32 + quad * 8);
      const float4 q = *(const float4*)(x + (size_t)gn * 64 + ks * 32 + quad * 8 + 4);
      y[0] = p.x; y[1] = p.y; y[2] = p.z; y[3] = p.w;
      y[4] = q.x; y[5] = q.y; y[6] = q.z; y[7] = q.w;
    }
    bfrag[ks] = pk8(y);
  }
  __syncthreads();

#pragma unroll
  for (int t = 0; t < 4; ++t) {
    f32x4 acc = {0.f, 0.f, 0.f, 0.f};
#pragma unroll
    for (int ks = 0; ks < 2; ++ks) {
      const f16x8 af = frag_ldh(wlds, t * 16 + l15, ks * 32 + quad * 8);
      acc = __builtin_amdgcn_mfma_f32_16x16x32_f16(af, bfrag[ks], acc, 0, 0, 0);
    }
    const int hb = t * 16 + quad * 4;
    *(f16x4*)(hlds + nloc * 72 + hb) =
        pk4(fmaxf(acc[0] + biasv[hb + 0], 0.f), fmaxf(acc[1] + biasv[hb + 1], 0.f),
            fmaxf(acc[2] + biasv[hb + 2], 0.f), fmaxf(acc[3] + biasv[hb + 3], 0.f));
  }
  __syncthreads();

  f16x8 hfrag[2];
#pragma unroll
  for (int ks = 0; ks < 2; ++ks)
    hfrag[ks] = frag_ldh(hlds, nloc, ks * 32 + quad * 8);

  _Float16* outs[3] = {vh, kh, qh};
#pragma unroll
  for (int p = 0; p < 3; ++p) {
    const _Float16* W = wlds + (p + 1) * 4608;
#pragma unroll
    for (int t = 0; t < 4; ++t) {
      f32x4 acc = {0.f, 0.f, 0.f, 0.f};
#pragma unroll
      for (int ks = 0; ks < 2; ++ks) {
        const f16x8 af = frag_ldh(W, t * 16 + l15, ks * 32 + quad * 8);
        acc = __builtin_amdgcn_mfma_f32_16x16x32_f16(af, hfrag[ks], acc, 0, 0, 0);
      }
      if (gn < NN) {
        *(f16x4*)(outs[p] + (size_t)gn * 64 + t * 16 + quad * 4) =
            pk4(acc[0], acc[1], acc[2], acc[3]);
      }
    }
  }
}

__global__ __launch_bounds__(256, 4) void edge_pass(
    const int2* __restrict__ srt, const float* __restrict__ pos,
    const _Float16* __restrict__ vh, const _Float16* __restrict__ kh,
    const _Float16* __restrict__ qh, const _Float16* __restrict__ w16,
    const float* __restrict__ att_b1, const float* __restrict__ att_b2,
    const float* __restrict__ pos_w1, const float* __restrict__ pos_b1,
    const float* __restrict__ pos_b2, float* __restrict__ num,
    float* __restrict__ den) {
  __shared__ __align__(16) _Float16 smem[18432];
  __shared__ __align__(16) float posw1T[3 * 64];
  __shared__ float b1s[64], b2s[64], pb1s[64], pb2s[64];
  __shared__ int dsts[64];

  _Float16* W1 = smem;
  _Float16* W2 = smem + 4608;
  _Float16* PW2 = smem + 9216;
  _Float16* h1 = smem + 13824;
  float2* pairb = (float2*)smem;

  const int tid = threadIdx.x;
  const int eb = blockIdx.x * 64;
  const int l15 = tid & 15;
  const int quad = (tid >> 4) & 3;
  const int wband = tid >> 6;
  const int eloc = wband * 16 + l15;

  int s_mine, d_mine;
  f16x8 bfrag[2];
  float dp0, dp1, dp2;
  {
    const int e = eb + eloc;
    int2 sd = make_int2(0, 0);
    int valid_d = -1;
    if (e < ET) {
      sd = srt[e];
      valid_d = sd.y;
    }
    s_mine = sd.x;
    d_mine = sd.y;
    if (quad == 0) dsts[eloc] = valid_d;
#pragma unroll
    for (int ks = 0; ks < 2; ++ks) {
      const f16x8 qv =
          *(const f16x8*)(qh + (size_t)d_mine * 64 + ks * 32 + quad * 8);
      const f16x8 kv =
          *(const f16x8*)(kh + (size_t)s_mine * 64 + ks * 32 + quad * 8);
      bfrag[ks] = qv - kv;
    }
    dp0 = pos[(size_t)d_mine * 3 + 0] - pos[(size_t)s_mine * 3 + 0];
    dp1 = pos[(size_t)d_mine * 3 + 1] - pos[(size_t)s_mine * 3 + 1];
    dp2 = pos[(size_t)d_mine * 3 + 2] - pos[(size_t)s_mine * 3 + 2];
  }

  stage_w(W1, w16 + 4 * 4096, tid);
  stage_w(W2, w16 + 5 * 4096, tid);
  stage_w(PW2, w16 + 6 * 4096, tid);
  if (tid < 64) {
    b1s[tid] = att_b1[tid];
    b2s[tid] = att_b2[tid];
    pb1s[tid] = pos_b1[tid];
    pb2s[tid] = pos_b2[tid];
    posw1T[0 * 64 + tid] = pos_w1[tid * 3 + 0];
    posw1T[1 * 64 + tid] = pos_w1[tid * 3 + 1];
    posw1T[2 * 64 + tid] = pos_w1[tid * 3 + 2];
  }
  __syncthreads();

#pragma unroll
  for (int t = 0; t < 4; ++t) {
    f32x4 acc = {0.f, 0.f, 0.f, 0.f};
#pragma unroll
    for (int ks = 0; ks < 2; ++ks) {
      const f16x8 af = frag_ldh(W1, t * 16 + l15, ks * 32 + quad * 8);
      acc = __builtin_amdgcn_mfma_f32_16x16x32_f16(af, bfrag[ks], acc, 0, 0, 0);
    }
    const int hb = t * 16 + quad * 4;
    *(f16x4*)(h1 + eloc * 72 + hb) =
        pk4(fmaxf(acc[0] + b1s[hb + 0], 0.f), fmaxf(acc[1] + b1s[hb + 1], 0.f),
            fmaxf(acc[2] + b1s[hb + 2], 0.f), fmaxf(acc[3] + b1s[hb + 3], 0.f));
  }

  f16x8 hpfrag[2];
#pragma unroll
  for (int ks = 0; ks < 2; ++ks) {
    float hv[8];
#pragma unroll
    for (int j = 0; j < 8; ++j) {
      const int i = ks * 32 + quad * 8 + j;
      float h = pb1s[i];
      h = fmaf(dp0, posw1T[i], h);
      h = fmaf(dp1, posw1T[64 + i], h);
      h = fmaf(dp2, posw1T[128 + i], h);
      hv[j] = fmaxf(h, 0.f);
    }
    hpfrag[ks] = pk8(hv);
  }
  __syncthreads();

  float ex[16], del[16];
  {
    f16x8 hfrag[2];
#pragma unroll
    for (int ks = 0; ks < 2; ++ks)
      hfrag[ks] = frag_ldh(h1, eloc, ks * 32 + quad * 8);
#pragma unroll
    for (int t = 0; t < 4; ++t) {
      f32x4 acc = {0.f, 0.f, 0.f, 0.f};
#pragma unroll
      for (int ks = 0; ks < 2; ++ks) {
        const f16x8 af = frag_ldh(W2, t * 16 + l15, ks * 32 + quad * 8);
        acc = __builtin_amdgcn_mfma_f32_16x16x32_f16(af, hfrag[ks], acc, 0, 0, 0);
      }
      const int ob = t * 16 + quad * 4;
#pragma unroll
      for (int r = 0; r < 4; ++r)
        ex[t * 4 + r] = __expf(fmaxf(acc[r] + b2s[ob + r], 0.f));
    }
  }
#pragma unroll
  for (int t = 0; t < 4; ++t) {
    f32x4 acc = {0.f, 0.f, 0.f, 0.f};
#pragma unroll
    for (int ks = 0; ks < 2; ++ks) {
      const f16x8 af = frag_ldh(PW2, t * 16 + l15, ks * 32 + quad * 8);
      acc = __builtin_amdgcn_mfma_f32_16x16x32_f16(af, hpfrag[ks], acc, 0, 0, 0);
    }
    const int ob = t * 16 + quad * 4;
#pragma unroll
    for (int r = 0; r < 4; ++r)
      del[t * 4 + r] = fmaxf(acc[r] + pb2s[ob + r], 0.f);
  }
  float vr[16];
#pragma unroll
  for (int t = 0; t < 4; ++t) {
    const f16x4 v4 = *(const f16x4*)(vh + (size_t)s_mine * 64 + t * 16 + quad * 4);
    vr[t * 4 + 0] = (float)v4[0];
    vr[t * 4 + 1] = (float)v4[1];
    vr[t * 4 + 2] = (float)v4[2];
    vr[t * 4 + 3] = (float)v4[3];
  }
  __syncthreads();

#pragma unroll
  for (int t = 0; t < 4; ++t) {
#pragma unroll
    for (int r = 0; r < 4; ++r) {
      const int o = t * 16 + quad * 4 + r;
      const int sl = (eloc + 2 * o) & 63;
      const float e_ = ex[t * 4 + r];
      pairb[o * 65 + sl] = make_float2(e_ * (vr[t * 4 + r] + del[t * 4 + r]), e_);
    }
  }
  __syncthreads();

  {
    const int c = tid & 63;
    const int r = tid >> 6;
    float am = 0.f, ae = 0.f;
    int cur = -1;
#pragma unroll 1
    for (int t2 = 0; t2 < 16; ++t2) {
      const int el = r * 16 + t2;
      const int d = dsts[el];
      if (d != cur) {
        if (cur >= 0) {
          unsafeAtomicAdd(num + (size_t)cur * 64 + c, am);
          unsafeAtomicAdd(den + (size_t)cur * 64 + c, ae);
        }
        cur = d;
        am = 0.f;
        ae = 0.f;
      }
      if (d >= 0) {
        const float2 pe = pairb[c * 65 + ((el + 2 * c) & 63)];
        am += pe.x;
        ae += pe.y;
      }
    }
    if (cur >= 0) {
      unsafeAtomicAdd(num + (size_t)cur * 64 + c, am);
      unsafeAtomicAdd(den + (size_t)cur * 64 + c, ae);
    }
  }
}

__global__ __launch_bounds__(256, 4) void out_proj(
    const float* __restrict__ num, const float* __restrict__ den,
    const _Float16* __restrict__ w16, const float* __restrict__ b_out,
    float* __restrict__ out) {
  __shared__ __align__(16) _Float16 wlds[4608];
  __shared__ float biasv[64];

  const int tid = threadIdx.x;
  const int nb = blockIdx.x * 64;
  const int l15 = tid & 15;
  const int quad = (tid >> 4) & 3;
  const int wband = tid >> 6;
  const int gn = nb + wband * 16 + l15;

  stage_w(wlds, w16 + 7 * 4096, tid);
  if (tid < 64) biasv[tid] = b_out[tid];

  f16x8 bfrag[2];
#pragma unroll
  for (int ks = 0; ks < 2; ++ks) {
    float y[8] = {0.f, 0.f, 0.f, 0.f, 0.f, 0.f, 0.f, 0.f};
    if (gn < NN) {
      const size_t base = (size_t)gn * 64 + ks * 32 + quad * 8;
      const float4 n0 = *(const float4*)(num + base);
      const float4 n1 = *(const float4*)(num + base + 4);
      const float4 d0 = *(const float4*)(den + base);
      const float4 d1 = *(const float4*)(den + base + 4);
      y[0] = n0.x / (d0.x + 1e-16f); y[1] = n0.y / (d0.y + 1e-16f);
      y[2] = n0.z / (d0.z + 1e-16f); y[3] = n0.w / (d0.w + 1e-16f);
      y[4] = n1.x / (d1.x + 1e-16f); y[5] = n1.y / (d1.y + 1e-16f);
      y[6] = n1.z / (d1.z + 1e-16f); y[7] = n1.w / (d1.w + 1e-16f);
    }
    bfrag[ks] = pk8(y);
  }
  __syncthreads();

#pragma unroll
  for (int t = 0; t < 4; ++t) {
    f32x4 acc = {0.f, 0.f, 0.f, 0.f};
#pragma unroll
    for (int ks = 0; ks < 2; ++ks) {
      const f16x8 af = frag_ldh(wlds, t * 16 + l15, ks * 32 + quad * 8);
      acc = __builtin_amdgcn_mfma_f32_16x16x32_f16(af, bfrag[ks], acc, 0, 0, 0);
    }
    if (gn < NN) {
      const int ob = t * 16 + quad * 4;
      float4 r;
      r.x = fmaxf(acc[0] + biasv[ob + 0], 0.f);
      r.y = fmaxf(acc[1] + biasv[ob + 1], 0.f);
      r.z = fmaxf(acc[2] + biasv[ob + 2], 0.f);
      r.w = fmaxf(acc[3] + biasv[ob + 3], 0.f);
      *(float4*)(out + (size_t)gn * 64 + ob) = r;
    }
  }
}

// ===========================================================================
extern "C" void kernel_launch(void* const* d_in, const int* in_sizes, int n_in,
                              void* d_out, int out_size, void* d_ws,
                              size_t ws_size, hipStream_t stream) {
  const float* x      = (const float*)d_in[0];
  const float* pos    = (const float*)d_in[1];
  const int*   ei     = (const int*)d_in[2];
  const float* W_in   = (const float*)d_in[3];
  const float* b_in   = (const float*)d_in[4];
  const float* W_out  = (const float*)d_in[5];
  const float* b_out  = (const float*)d_in[6];
  const float* W_lin  = (const float*)d_in[7];
  const float* W_src  = (const float*)d_in[8];
  const float* W_dst  = (const float*)d_in[9];
  const float* pos_w1 = (const float*)d_in[10];
  const float* pos_b1 = (const float*)d_in[11];
  const float* pos_w2 = (const float*)d_in[12];
  const float* pos_b2 = (const float*)d_in[13];
  const float* att_w1 = (const float*)d_in[14];
  const float* att_b1 = (const float*)d_in[15];
  const float* att_w2 = (const float*)d_in[16];
  const float* att_b2 = (const float*)d_in[17];

  float* ws = (float*)d_ws;
  const size_t NC = (size_t)NN * C;
  float* num = ws;
  float* den = ws + NC;
  _Float16* vh = (_Float16*)(ws + 2 * NC);
  _Float16* kh = vh + NC;
  _Float16* qh = kh + NC;
  _Float16* w16 = qh + NC;
  int* ib    = (int*)(w16 + 8 * 4096);
  int* cnt2  = ib;
  int* curs2 = ib + 8 * NN;
  int* bsum  = ib + 16 * NN;
  int2* srt  = (int2*)(((uintptr_t)(bsum + NBLK) + 15) & ~(uintptr_t)15);

  MegaArgs ma;
  ma.x = x; ma.pos = pos; ma.ei = ei;
  ma.W_in = W_in; ma.b_in = b_in; ma.W_out = W_out; ma.b_out = b_out;
  ma.W_lin = W_lin; ma.W_src = W_src; ma.W_dst = W_dst;
  ma.pos_w1 = pos_w1; ma.pos_b1 = pos_b1; ma.pos_w2 = pos_w2; ma.pos_b2 = pos_b2;
  ma.att_w1 = att_w1; ma.att_b1 = att_b1; ma.att_w2 = att_w2; ma.att_b2 = att_b2;
  ma.num = num; ma.den = den; ma.vh = vh; ma.kh = kh; ma.qh = qh; ma.w16 = w16;
  ma.cnt2 = cnt2; ma.curs2 = curs2; ma.bsum = bsum; ma.srt = srt;
  ma.out = (float*)d_out;

  int dev = 0;
  (void)hipGetDevice(&dev);
  int cus = 0;
  if (hipDeviceGetAttribute(&cus, hipDeviceAttributeMultiprocessorCount, dev) !=
          hipSuccess ||
      cus <= 0)
    cus = 256;
  int perCU = 0;
  if (hipOccupancyMaxActiveBlocksPerMultiprocessor(&perCU, mega_kernel, 256,
                                                   0) != hipSuccess ||
      perCU <= 0)
    perCU = 3;
  if (perCU > 4) perCU = 4;
  void* params[] = {&ma};
  hipError_t le = hipLaunchCooperativeKernel(
      mega_kernel, dim3(perCU * cus), dim3(256), params, 0, stream);
  if (le == hipSuccess) return;
  (void)hipGetLastError();  // clear error state; run fallback pipeline

  const dim3 blk(256);
  prep_kernel<<<dim3(8), blk, 0, stream>>>(W_in, W_lin, W_src, W_dst, att_w1,
                                           att_w2, pos_w2, W_out, w16, cnt2);
  node_proj<<<dim3((NN + 63) / 64), blk, 0, stream>>>(x, b_in, w16, ei, cnt2,
                                                      vh, kh, qh);
  scan_partial<<<dim3(NBLK + ZBLK), blk, 0, stream>>>(cnt2, bsum, num);
  scan_final<<<dim3(NBLK), blk, 0, stream>>>(cnt2, bsum, curs2);
  scatter_kernel<<<dim3(NCHUNK), blk, 0, stream>>>(ei, curs2, srt);
  edge_pass<<<dim3((ET + 63) / 64), blk, 0, stream>>>(
      srt, pos, vh, kh, qh, w16, att_b1, att_b2, pos_w1, pos_b1, pos_b2, num,
      den);
  out_proj<<<dim3((NN + 63) / 64), blk, 0, stream>>>(num, den, w16, b_out,
                                                     (float*)d_out);
}

// Round 10
// 299.251 us; speedup vs baseline: 2.5704x; 2.5704x over previous
//
#include <hip/hip_runtime.h>
#include <math.h>

#define NN 50000
#define EE 800000
#define ET (EE + NN)   // 850000 edges incl. self-loops
#define C  64
#define NBLK 49        // ceil(NN/1024) scan blocks
#define NCHUNK 831     // ceil(ET/1024) edge chunks
#define ZBLK 463       // zeroing blocks appended to scan_partial

typedef __attribute__((ext_vector_type(8))) _Float16 f16x8;
typedef __attribute__((ext_vector_type(4))) _Float16 f16x4;
typedef __attribute__((ext_vector_type(2))) _Float16 f16x2;
typedef __attribute__((ext_vector_type(4))) float f32x4;

__device__ __forceinline__ f16x2 pk2(float a, float b) {
  return __builtin_bit_cast(f16x2, __builtin_amdgcn_cvt_pkrtz(a, b));
}
__device__ __forceinline__ f16x4 pk4(float a, float b, float c, float d) {
  return __builtin_shufflevector(pk2(a, b), pk2(c, d), 0, 1, 2, 3);
}
__device__ __forceinline__ f16x8 pk8(const float* y) {
  const f16x4 lo = pk4(y[0], y[1], y[2], y[3]);
  const f16x4 hi = pk4(y[4], y[5], y[6], y[7]);
  return __builtin_shufflevector(lo, hi, 0, 1, 2, 3, 4, 5, 6, 7);
}

// f16 LDS row read: 8 consecutive k at 16B alignment (stride 72 halves)
__device__ __forceinline__ f16x8 frag_ldh(const _Float16* base, int row,
                                          int kofs) {
  return *(const f16x8*)(base + row * 72 + kofs);
}

// Copy one 64x64 f16 weight from global (row-major 64) to LDS (stride 72).
__device__ __forceinline__ void stage_w(_Float16* __restrict__ dst,
                                        const _Float16* __restrict__ src16,
                                        int tid) {
  const f16x8* src = (const f16x8*)(src16 + tid * 16);
  _Float16* d = dst + (tid >> 2) * 72 + (tid & 3) * 16;
  ((f16x8*)d)[0] = src[0];
  ((f16x8*)d)[1] = src[1];
}

// pairb swizzle: 2-way banks on BOTH write (vary e,o-quad) and read (vary o)
__device__ __forceinline__ int psl(int e, int o) {
  return (e + 2 * o + (o >> 5)) & 63;
}

// ---------------------------------------------------------------------------
// prep: convert 8 weight matrices f32 -> f16 (one block each) + zero cnt shards
// order: W_in, W_lin, W_src, W_dst, att_w1, att_w2, pos_w2, W_out
// ---------------------------------------------------------------------------
__global__ __launch_bounds__(256) void prep_kernel(
    const float* __restrict__ W_in, const float* __restrict__ W_lin,
    const float* __restrict__ W_src, const float* __restrict__ W_dst,
    const float* __restrict__ att_w1, const float* __restrict__ att_w2,
    const float* __restrict__ pos_w2, const float* __restrict__ W_out,
    _Float16* __restrict__ w16, int* __restrict__ cnt2) {
  const float* Ws[8] = {W_in, W_lin, W_src, W_dst, att_w1, att_w2, pos_w2, W_out};
  const float* src = Ws[blockIdx.x];
  _Float16* dst = w16 + blockIdx.x * 4096;
#pragma unroll
  for (int i = threadIdx.x * 4; i < 4096; i += 1024) {
    const float4 w = *(const float4*)(src + i);
    *(f16x4*)(dst + i) = pk4(w.x, w.y, w.z, w.w);
  }
  int4* cz = (int4*)(cnt2 + blockIdx.x * NN);
#pragma unroll 1
  for (int i = threadIdx.x; i < NN / 4; i += 256) cz[i] = make_int4(0, 0, 0, 0);
}

// ---------------------------------------------------------------------------
// Scan over sharded counters; extra blocks zero num/den.
// ---------------------------------------------------------------------------
__global__ __launch_bounds__(256) void scan_partial(const int* __restrict__ cnt2,
                                                    int* __restrict__ bsum,
                                                    float* __restrict__ zeroreg) {
  const int t = threadIdx.x;
  if (blockIdx.x >= NBLK) {
    const int zb = blockIdx.x - NBLK;
    float4* dst = (float4*)zeroreg;
    const int total4 = 2 * NN * 64 / 4;
    const float4 z = make_float4(0.f, 0.f, 0.f, 0.f);
#pragma unroll 1
    for (int i = zb * 256 + t; i < total4; i += ZBLK * 256) dst[i] = z;
    return;
  }
  __shared__ int ws[4];
  const int base = blockIdx.x * 1024 + t * 4;
  int s = 0;
  if (base + 3 < NN) {
#pragma unroll
    for (int sh = 0; sh < 8; ++sh) {
      const int4 v = *(const int4*)(cnt2 + sh * NN + base);
      s += v.x + v.y + v.z + v.w;
    }
  } else {
#pragma unroll
    for (int i = 0; i < 4; ++i)
      if (base + i < NN)
#pragma unroll
        for (int sh = 0; sh < 8; ++sh) s += cnt2[sh * NN + base + i];
  }
#pragma unroll
  for (int off = 32; off; off >>= 1) s += __shfl_down(s, off, 64);
  if ((t & 63) == 0) ws[t >> 6] = s;
  __syncthreads();
  if (t == 0) bsum[blockIdx.x] = ws[0] + ws[1] + ws[2] + ws[3];
}

__global__ __launch_bounds__(256) void scan_final(const int* __restrict__ cnt2,
                                                  const int* __restrict__ bsum,
                                                  int* __restrict__ curs2) {
  __shared__ int tsum[256];
  __shared__ int sblk[64];
  const int t = threadIdx.x;
  if (t < 64) {
    const int mine = (t < NBLK) ? bsum[t] : 0;
    int v = mine;
#pragma unroll
    for (int off = 1; off < 64; off <<= 1) {
      const int u = __shfl_up(v, off, 64);
      if (t >= off) v += u;
    }
    sblk[t] = v - mine;
  }
  const int base = blockIdx.x * 1024 + t * 4;
  int c2[8][4];
  int v[4] = {0, 0, 0, 0};
  if (base + 3 < NN) {
#pragma unroll
    for (int sh = 0; sh < 8; ++sh) {
      const int4 x = *(const int4*)(cnt2 + sh * NN + base);
      c2[sh][0] = x.x; c2[sh][1] = x.y; c2[sh][2] = x.z; c2[sh][3] = x.w;
      v[0] += x.x; v[1] += x.y; v[2] += x.z; v[3] += x.w;
    }
  } else {
#pragma unroll
    for (int sh = 0; sh < 8; ++sh)
#pragma unroll
      for (int i = 0; i < 4; ++i) {
        const int c = (base + i < NN) ? cnt2[sh * NN + base + i] : 0;
        c2[sh][i] = c;
        v[i] += c;
      }
  }
  const int s = v[0] + v[1] + v[2] + v[3];
  tsum[t] = s;
  __syncthreads();
  for (int off = 1; off < 256; off <<= 1) {
    const int u = (t >= off) ? tsum[t - off] : 0;
    __syncthreads();
    tsum[t] += u;
    __syncthreads();
  }
  int ex = sblk[blockIdx.x] + tsum[t] - s;
  int offs[8][4];
#pragma unroll
  for (int i = 0; i < 4; ++i) {
    int run = ex;
#pragma unroll
    for (int sh = 0; sh < 8; ++sh) {
      offs[sh][i] = run;
      run += c2[sh][i];
    }
    ex += v[i];
  }
  if (base + 3 < NN) {
#pragma unroll
    for (int sh = 0; sh < 8; ++sh)
      *(int4*)(curs2 + sh * NN + base) =
          make_int4(offs[sh][0], offs[sh][1], offs[sh][2], offs[sh][3]);
  } else {
#pragma unroll
    for (int sh = 0; sh < 8; ++sh)
#pragma unroll
      for (int i = 0; i < 4; ++i)
        if (base + i < NN) curs2[sh * NN + base + i] = offs[sh][i];
  }
}

// scatter: block b owns edge chunk b (1024 edges); shard = b&7 (XCD-aligned).
__global__ __launch_bounds__(256) void scatter_kernel(const int* __restrict__ ei,
                                                      int* __restrict__ curs2,
                                                      int2* __restrict__ srt) {
  const int chunk = blockIdx.x;
  int* cs = curs2 + (chunk & 7) * NN;
  const int e0 = chunk * 1024 + threadIdx.x * 4;
  if (e0 >= ET) return;
  int s[4], d[4];
  if (e0 + 3 < EE) {
    const int4 sv = *(const int4*)(ei + e0);
    const int4 dv = *(const int4*)(ei + EE + e0);
    s[0] = sv.x; s[1] = sv.y; s[2] = sv.z; s[3] = sv.w;
    d[0] = dv.x; d[1] = dv.y; d[2] = dv.z; d[3] = dv.w;
  } else {
#pragma unroll
    for (int i = 0; i < 4; ++i) {
      const int e = e0 + i;
      if (e < EE) {
        s[i] = ei[e];
        d[i] = ei[EE + e];
      } else if (e < ET) {
        s[i] = d[i] = e - EE;
      } else {
        s[i] = d[i] = -1;
      }
    }
  }
#pragma unroll
  for (int i = 0; i < 4; ++i) {
    if (d[i] >= 0) {
      const int p = atomicAdd(&cs[d[i]], 1);
      srt[p] = make_int2(s[i], d[i]);
    }
  }
}

// ---------------------------------------------------------------------------
// Kernel A: fused sharded histogram + node projections (MFMA f16).
// ---------------------------------------------------------------------------
__global__ __launch_bounds__(256, 3) void node_proj(
    const float* __restrict__ x, const float* __restrict__ b_in,
    const _Float16* __restrict__ w16, const int* __restrict__ ei,
    int* __restrict__ cnt2, _Float16* __restrict__ vh,
    _Float16* __restrict__ kh, _Float16* __restrict__ qh) {
  __shared__ __align__(16) _Float16 wlds[4 * 4608];  // W_in|W_lin|W_src|W_dst
  __shared__ __align__(16) _Float16 hlds[4608];
  __shared__ float biasv[64];

  const int tid = threadIdx.x;
  const int nb = blockIdx.x * 64;
  const int l15 = tid & 15;
  const int quad = (tid >> 4) & 3;
  const int wband = tid >> 6;
  const int nloc = wband * 16 + l15;
  const int gn = nb + nloc;

  // sharded fire-and-forget histogram; chunk c = edges [c*1024,(c+1)*1024)
#pragma unroll 1
  for (int chunk = blockIdx.x; chunk < NCHUNK; chunk += gridDim.x) {
    int* cs = cnt2 + (chunk & 7) * NN;
    const int e0 = chunk * 1024 + tid * 4;
    if (e0 < ET) {
      int d[4];
      if (e0 + 3 < EE) {
        const int4 dv = *(const int4*)(ei + EE + e0);
        d[0] = dv.x; d[1] = dv.y; d[2] = dv.z; d[3] = dv.w;
      } else {
#pragma unroll
        for (int i = 0; i < 4; ++i) {
          const int e = e0 + i;
          d[i] = (e < EE) ? ei[EE + e] : ((e < ET) ? e - EE : -1);
        }
      }
#pragma unroll
      for (int i = 0; i < 4; ++i)
        if (d[i] >= 0) atomicAdd(&cs[d[i]], 1);
    }
  }

#pragma unroll
  for (int w = 0; w < 4; ++w) stage_w(wlds + w * 4608, w16 + w * 4096, tid);
  if (tid < 64) biasv[tid] = b_in[tid];

  // B-frag from x (f32 -> f16)
  f16x8 bfrag[2];
#pragma unroll
  for (int ks = 0; ks < 2; ++ks) {
    float y[8] = {0.f, 0.f, 0.f, 0.f, 0.f, 0.f, 0.f, 0.f};
    if (gn < NN) {
      const float4 a = *(const float4*)(x + (size_t)gn * 64 + ks * 32 + quad * 8);
      const float4 b = *(const float4*)(x + (size_t)gn * 64 + ks * 32 + quad * 8 + 4);
      y[0] = a.x; y[1] = a.y; y[2] = a.z; y[3] = a.w;
      y[4] = b.x; y[5] = b.y; y[6] = b.z; y[7] = b.w;
    }
    bfrag[ks] = pk8(y);
  }
  __syncthreads();  // B0

  // GEMM1: h = relu(W_in . x^T + b) -> hlds rows [n][o] f16
#pragma unroll
  for (int t = 0; t < 4; ++t) {
    f32x4 acc = {0.f, 0.f, 0.f, 0.f};
#pragma unroll
    for (int ks = 0; ks < 2; ++ks) {
      const f16x8 af = frag_ldh(wlds, t * 16 + l15, ks * 32 + quad * 8);
      acc = __builtin_amdgcn_mfma_f32_16x16x32_f16(af, bfrag[ks], acc, 0, 0, 0);
    }
    const int hb = t * 16 + quad * 4;
    *(f16x4*)(hlds + nloc * 72 + hb) =
        pk4(fmaxf(acc[0] + biasv[hb + 0], 0.f), fmaxf(acc[1] + biasv[hb + 1], 0.f),
            fmaxf(acc[2] + biasv[hb + 2], 0.f), fmaxf(acc[3] + biasv[hb + 3], 0.f));
  }
  __syncthreads();  // B1

  f16x8 hfrag[2];
#pragma unroll
  for (int ks = 0; ks < 2; ++ks)
    hfrag[ks] = frag_ldh(hlds, nloc, ks * 32 + quad * 8);

  _Float16* outs[3] = {vh, kh, qh};
#pragma unroll
  for (int p = 0; p < 3; ++p) {
    const _Float16* W = wlds + (p + 1) * 4608;
#pragma unroll
    for (int t = 0; t < 4; ++t) {
      f32x4 acc = {0.f, 0.f, 0.f, 0.f};
#pragma unroll
      for (int ks = 0; ks < 2; ++ks) {
        const f16x8 af = frag_ldh(W, t * 16 + l15, ks * 32 + quad * 8);
        acc = __builtin_amdgcn_mfma_f32_16x16x32_f16(af, hfrag[ks], acc, 0, 0, 0);
      }
      if (gn < NN) {
        *(f16x4*)(outs[p] + (size_t)gn * 64 + t * 16 + quad * 4) =
            pk4(acc[0], acc[1], acc[2], acc[3]);
      }
    }
  }
}

// ---------------------------------------------------------------------------
// Kernel B: MFMA (f16) edge pass. LDS diet: 29.7KB -> 5 blocks/CU.
//  - W1 | W2 | HP(h1 then PW2), each 64 rows x stride 72 f16 (27.6KB)
//  - h1 is wave-private (row eloc touched only by band wband) -> no barrier
//  - pairb: f16x2 (msg,ex), 16KB, aliases W1+W2 after both GEMMs done
// 4 barriers total.
// ---------------------------------------------------------------------------
__global__ __launch_bounds__(256, 5) void edge_pass(
    const int2* __restrict__ srt, const float* __restrict__ pos,
    const _Float16* __restrict__ vh, const _Float16* __restrict__ kh,
    const _Float16* __restrict__ qh, const _Float16* __restrict__ w16,
    const float* __restrict__ att_b1, const float* __restrict__ att_b2,
    const float* __restrict__ pos_w1, const float* __restrict__ pos_b1,
    const float* __restrict__ pos_b2, float* __restrict__ num,
    float* __restrict__ den) {
  __shared__ __align__(16) _Float16 smem[13824];  // W1|W2|HP
  __shared__ __align__(16) float posw1T[3 * 64];
  __shared__ float b1s[64], b2s[64], pb1s[64], pb2s[64];
  __shared__ int dsts[64];

  _Float16* W1 = smem;
  _Float16* W2 = smem + 4608;
  _Float16* HP = smem + 9216;     // h1, then PW2
  f16x2* pairb = (f16x2*)smem;    // 64ch x 64slot, aliases W1+W2 (16KB<=18.4KB)

  const int tid = threadIdx.x;
  const int eb = blockIdx.x * 64;
  const int l15 = tid & 15;
  const int quad = (tid >> 4) & 3;
  const int wband = tid >> 6;
  const int eloc = wband * 16 + l15;

  // ---- phase 0a: per-lane edge read + B-frag: ad = q[dst]-k[src] (f16)
  int s_mine, d_mine;
  f16x8 bfrag[2];
  float dp0, dp1, dp2;
  {
    const int e = eb + eloc;
    int2 sd = make_int2(0, 0);
    int valid_d = -1;
    if (e < ET) {
      sd = srt[e];
      valid_d = sd.y;
    }
    s_mine = sd.x;
    d_mine = sd.y;
    if (quad == 0) dsts[eloc] = valid_d;
#pragma unroll
    for (int ks = 0; ks < 2; ++ks) {
      const f16x8 qv =
          *(const f16x8*)(qh + (size_t)d_mine * 64 + ks * 32 + quad * 8);
      const f16x8 kv =
          *(const f16x8*)(kh + (size_t)s_mine * 64 + ks * 32 + quad * 8);
      bfrag[ks] = qv - kv;
    }
    dp0 = pos[(size_t)d_mine * 3 + 0] - pos[(size_t)s_mine * 3 + 0];
    dp1 = pos[(size_t)d_mine * 3 + 1] - pos[(size_t)s_mine * 3 + 1];
    dp2 = pos[(size_t)d_mine * 3 + 2] - pos[(size_t)s_mine * 3 + 2];
  }

  // ---- phase 0b: stage W1, W2 (f16), biases, posw1T
  stage_w(W1, w16 + 4 * 4096, tid);
  stage_w(W2, w16 + 5 * 4096, tid);
  if (tid < 64) {
    b1s[tid] = att_b1[tid];
    b2s[tid] = att_b2[tid];
    pb1s[tid] = pos_b1[tid];
    pb2s[tid] = pos_b2[tid];
    posw1T[0 * 64 + tid] = pos_w1[tid * 3 + 0];
    posw1T[1 * 64 + tid] = pos_w1[tid * 3 + 1];
    posw1T[2 * 64 + tid] = pos_w1[tid * 3 + 2];
  }
  __syncthreads();  // B0

  // ---- GEMM1: h1 = relu(W1 . ad^T + b1) -> HP rows [e][h] f16 (wave-private)
#pragma unroll
  for (int t = 0; t < 4; ++t) {
    f32x4 acc = {0.f, 0.f, 0.f, 0.f};
#pragma unroll
    for (int ks = 0; ks < 2; ++ks) {
      const f16x8 af = frag_ldh(W1, t * 16 + l15, ks * 32 + quad * 8);
      acc = __builtin_amdgcn_mfma_f32_16x16x32_f16(af, bfrag[ks], acc, 0, 0, 0);
    }
    const int hb = t * 16 + quad * 4;
    *(f16x4*)(HP + eloc * 72 + hb) =
        pk4(fmaxf(acc[0] + b1s[hb + 0], 0.f), fmaxf(acc[1] + b1s[hb + 1], 0.f),
            fmaxf(acc[2] + b1s[hb + 2], 0.f), fmaxf(acc[3] + b1s[hb + 3], 0.f));
  }

  // ---- hp in registers (k=3 pos-MLP layer 1 for this lane's 16 k-values)
  f16x8 hpfrag[2];
#pragma unroll
  for (int ks = 0; ks < 2; ++ks) {
    float hv[8];
#pragma unroll
    for (int j = 0; j < 8; ++j) {
      const int i = ks * 32 + quad * 8 + j;
      float h = pb1s[i];
      h = fmaf(dp0, posw1T[i], h);
      h = fmaf(dp1, posw1T[64 + i], h);
      h = fmaf(dp2, posw1T[128 + i], h);
      hv[j] = fmaxf(h, 0.f);
    }
    hpfrag[ks] = pk8(hv);
  }

  // ---- GEMM2: alpha = relu(W2 . h1^T + b2); ex = exp(alpha)
  // h1 rows of own band: same-wave producer/consumer -> lgkmcnt only.
  float ex[16];
  {
    f16x8 hfrag[2];
#pragma unroll
    for (int ks = 0; ks < 2; ++ks)
      hfrag[ks] = frag_ldh(HP, eloc, ks * 32 + quad * 8);
#pragma unroll
    for (int t = 0; t < 4; ++t) {
      f32x4 acc = {0.f, 0.f, 0.f, 0.f};
#pragma unroll
      for (int ks = 0; ks < 2; ++ks) {
        const f16x8 af = frag_ldh(W2, t * 16 + l15, ks * 32 + quad * 8);
        acc = __builtin_amdgcn_mfma_f32_16x16x32_f16(af, hfrag[ks], acc, 0, 0, 0);
      }
      const int ob = t * 16 + quad * 4;
#pragma unroll
      for (int r = 0; r < 4; ++r)
        ex[t * 4 + r] = __expf(fmaxf(acc[r] + b2s[ob + r], 0.f));
    }
  }
  // v gather issued now (global; overlaps B1/stage/B2 latency)
  float vr[16];
#pragma unroll
  for (int t = 0; t < 4; ++t) {
    const f16x4 v4 = *(const f16x4*)(vh + (size_t)s_mine * 64 + t * 16 + quad * 4);
    vr[t * 4 + 0] = (float)v4[0];
    vr[t * 4 + 1] = (float)v4[1];
    vr[t * 4 + 2] = (float)v4[2];
    vr[t * 4 + 3] = (float)v4[3];
  }
  __syncthreads();  // B1: all waves done with W1, W2, h1

  stage_w(HP, w16 + 6 * 4096, tid);  // PW2 over h1
  __syncthreads();  // B2: PW2 visible

  // ---- GEMM3: delta = relu(PW2 . hp^T + pb2)
  float del[16];
#pragma unroll
  for (int t = 0; t < 4; ++t) {
    f32x4 acc = {0.f, 0.f, 0.f, 0.f};
#pragma unroll
    for (int ks = 0; ks < 2; ++ks) {
      const f16x8 af = frag_ldh(HP, t * 16 + l15, ks * 32 + quad * 8);
      acc = __builtin_amdgcn_mfma_f32_16x16x32_f16(af, hpfrag[ks], acc, 0, 0, 0);
    }
    const int ob = t * 16 + quad * 4;
#pragma unroll
    for (int r = 0; r < 4; ++r)
      del[t * 4 + r] = fmaxf(acc[r] + pb2s[ob + r], 0.f);
  }

  // ---- phase 5: (msg, ex) -> pairb f16x2 (region free since B1)
#pragma unroll
  for (int t = 0; t < 4; ++t) {
#pragma unroll
    for (int r = 0; r < 4; ++r) {
      const int o = t * 16 + quad * 4 + r;
      const float e_ = ex[t * 4 + r];
      pairb[o * 64 + psl(eloc, o)] =
          pk2(e_ * (vr[t * 4 + r] + del[t * 4 + r]), e_);
    }
  }
  __syncthreads();  // B3

  // ---- phase 6: segmented reduce over sorted-dst runs, then atomics
  {
    const int c = tid & 63;
    const int r = tid >> 6;
    float am = 0.f, ae = 0.f;
    int cur = -1;
#pragma unroll 1
    for (int t2 = 0; t2 < 16; ++t2) {
      const int el = r * 16 + t2;
      const int d = dsts[el];
      if (d != cur) {
        if (cur >= 0) {
          unsafeAtomicAdd(num + (size_t)cur * 64 + c, am);
          unsafeAtomicAdd(den + (size_t)cur * 64 + c, ae);
        }
        cur = d;
        am = 0.f;
        ae = 0.f;
      }
      if (d >= 0) {
        const f16x2 pe = pairb[c * 64 + psl(el, c)];
        am += (float)pe[0];
        ae += (float)pe[1];
      }
    }
    if (cur >= 0) {
      unsafeAtomicAdd(num + (size_t)cur * 64 + c, am);
      unsafeAtomicAdd(den + (size_t)cur * 64 + c, ae);
    }
  }
}

// ---------------------------------------------------------------------------
// Kernel C: out = relu((num/(den+1e-16)) @ W_out.T + b_out), MFMA f16.
// ---------------------------------------------------------------------------
__global__ __launch_bounds__(256, 4) void out_proj(
    const float* __restrict__ num, const float* __restrict__ den,
    const _Float16* __restrict__ w16, const float* __restrict__ b_out,
    float* __restrict__ out) {
  __shared__ __align__(16) _Float16 wlds[4608];
  __shared__ float biasv[64];

  const int tid = threadIdx.x;
  const int nb = blockIdx.x * 64;
  const int l15 = tid & 15;
  const int quad = (tid >> 4) & 3;
  const int wband = tid >> 6;
  const int gn = nb + wband * 16 + l15;

  stage_w(wlds, w16 + 7 * 4096, tid);
  if (tid < 64) biasv[tid] = b_out[tid];

  f16x8 bfrag[2];
#pragma unroll
  for (int ks = 0; ks < 2; ++ks) {
    float y[8] = {0.f, 0.f, 0.f, 0.f, 0.f, 0.f, 0.f, 0.f};
    if (gn < NN) {
      const size_t base = (size_t)gn * 64 + ks * 32 + quad * 8;
      const float4 n0 = *(const float4*)(num + base);
      const float4 n1 = *(const float4*)(num + base + 4);
      const float4 d0 = *(const float4*)(den + base);
      const float4 d1 = *(const float4*)(den + base + 4);
      y[0] = n0.x / (d0.x + 1e-16f); y[1] = n0.y / (d0.y + 1e-16f);
      y[2] = n0.z / (d0.z + 1e-16f); y[3] = n0.w / (d0.w + 1e-16f);
      y[4] = n1.x / (d1.x + 1e-16f); y[5] = n1.y / (d1.y + 1e-16f);
      y[6] = n1.z / (d1.z + 1e-16f); y[7] = n1.w / (d1.w + 1e-16f);
    }
    bfrag[ks] = pk8(y);
  }
  __syncthreads();

#pragma unroll
  for (int t = 0; t < 4; ++t) {
    f32x4 acc = {0.f, 0.f, 0.f, 0.f};
#pragma unroll
    for (int ks = 0; ks < 2; ++ks) {
      const f16x8 af = frag_ldh(wlds, t * 16 + l15, ks * 32 + quad * 8);
      acc = __builtin_amdgcn_mfma_f32_16x16x32_f16(af, bfrag[ks], acc, 0, 0, 0);
    }
    if (gn < NN) {
      const int ob = t * 16 + quad * 4;
      float4 r;
      r.x = fmaxf(acc[0] + biasv[ob + 0], 0.f);
      r.y = fmaxf(acc[1] + biasv[ob + 1], 0.f);
      r.z = fmaxf(acc[2] + biasv[ob + 2], 0.f);
      r.w = fmaxf(acc[3] + biasv[ob + 3], 0.f);
      *(float4*)(out + (size_t)gn * 64 + ob) = r;
    }
  }
}

extern "C" void kernel_launch(void* const* d_in, const int* in_sizes, int n_in,
                              void* d_out, int out_size, void* d_ws,
                              size_t ws_size, hipStream_t stream) {
  const float* x      = (const float*)d_in[0];
  const float* pos    = (const float*)d_in[1];
  const int*   ei     = (const int*)d_in[2];
  const float* W_in   = (const float*)d_in[3];
  const float* b_in   = (const float*)d_in[4];
  const float* W_out  = (const float*)d_in[5];
  const float* b_out  = (const float*)d_in[6];
  const float* W_lin  = (const float*)d_in[7];
  const float* W_src  = (const float*)d_in[8];
  const float* W_dst  = (const float*)d_in[9];
  const float* pos_w1 = (const float*)d_in[10];
  const float* pos_b1 = (const float*)d_in[11];
  const float* pos_w2 = (const float*)d_in[12];
  const float* pos_b2 = (const float*)d_in[13];
  const float* att_w1 = (const float*)d_in[14];
  const float* att_b1 = (const float*)d_in[15];
  const float* att_w2 = (const float*)d_in[16];
  const float* att_b2 = (const float*)d_in[17];

  float* ws = (float*)d_ws;
  const size_t NC = (size_t)NN * C;
  float* num = ws;                       // NC f32
  float* den = ws + NC;                  // NC f32
  _Float16* vh = (_Float16*)(ws + 2 * NC);  // NC f16
  _Float16* kh = vh + NC;                    // NC f16
  _Float16* qh = kh + NC;                    // NC f16
  _Float16* w16 = qh + NC;                   // 8*4096 f16
  int* ib     = (int*)(w16 + 8 * 4096);
  int* cnt2   = ib;                      // 8*NN
  int* curs2  = ib + 8 * NN;             // 8*NN
  int* bsum   = ib + 16 * NN;            // NBLK
  int2* srt   = (int2*)(((uintptr_t)(bsum + NBLK) + 15) & ~(uintptr_t)15);

  const dim3 blk(256);
  prep_kernel<<<dim3(8), blk, 0, stream>>>(W_in, W_lin, W_src, W_dst, att_w1,
                                           att_w2, pos_w2, W_out, w16, cnt2);
  node_proj<<<dim3((NN + 63) / 64), blk, 0, stream>>>(x, b_in, w16, ei, cnt2,
                                                      vh, kh, qh);
  scan_partial<<<dim3(NBLK + ZBLK), blk, 0, stream>>>(cnt2, bsum, num);
  scan_final<<<dim3(NBLK), blk, 0, stream>>>(cnt2, bsum, curs2);
  scatter_kernel<<<dim3(NCHUNK), blk, 0, stream>>>(ei, curs2, srt);
  edge_pass<<<dim3((ET + 63) / 64), blk, 0, stream>>>(
      srt, pos, vh, kh, qh, w16, att_b1, att_b2, pos_w1, pos_b1, pos_b2, num,
      den);
  out_proj<<<dim3((NN + 63) / 64), blk, 0, stream>>>(num, den, w16, b_out,
                                                     (float*)d_out);
}